// Round 1
// baseline (4194.392 us; speedup 1.0000x reference)
//
#include <hip/hip_runtime.h>
#include <math.h>

#define NN 100000
#define NE 3200000
#define OUTD 112

// ---------------------------------------------------------------------------
// Kernel 1: ego = entity_embed * (1 + tanh(aux_info @ aux_W.T + aux_b))
// one thread per (node, feature). Writes ego0 (ws) and out[:, 0:64].
// ---------------------------------------------------------------------------
__global__ void fuse_ego_kernel(const float* __restrict__ aux_info,
                                const float* __restrict__ entity,
                                const float* __restrict__ aux_W,
                                const float* __restrict__ aux_b,
                                float* __restrict__ ego0,
                                float* __restrict__ out) {
    int idx = blockIdx.x * blockDim.x + threadIdx.x;
    if (idx >= NN * 64) return;
    int n = idx >> 6;
    int j = idx & 63;
    float a0 = aux_info[n * 3 + 0];
    float a1 = aux_info[n * 3 + 1];
    float a2 = aux_info[n * 3 + 2];
    float w0 = aux_W[j * 3 + 0];
    float w1 = aux_W[j * 3 + 1];
    float w2 = aux_W[j * 3 + 2];
    float t = tanhf(fmaf(a0, w0, fmaf(a1, w1, fmaf(a2, w2, aux_b[j]))));
    float e = entity[idx] * (1.0f + t);
    ego0[idx] = e;
    out[(size_t)n * OUTD + j] = e;
}

// ---------------------------------------------------------------------------
// Kernel 2: side[row] += val * ego[col]  (segment_sum via fp32 atomics)
// one thread per (edge, 4-feature group). D/4 threads share an edge, so the
// edge_{cols,rows,vals} loads are wave-uniform within the group (1 txn).
// ---------------------------------------------------------------------------
template <int D>
__global__ void scatter_kernel(const float* __restrict__ ego,
                               const float* __restrict__ vals,
                               const int* __restrict__ rows,
                               const int* __restrict__ cols,
                               float* __restrict__ side) {
    constexpr int FPE = D / 4;          // threads per edge (power of 2)
    constexpr int SH = (D == 64) ? 4 : (D == 32) ? 3 : 2;
    int tid = blockIdx.x * blockDim.x + threadIdx.x;
    int e = tid >> SH;
    int g = tid & (FPE - 1);
    if (e >= NE) return;
    int col = cols[e];
    int row = rows[e];
    float val = vals[e];
    const float4 v = *reinterpret_cast<const float4*>(ego + (size_t)col * D + g * 4);
    float* dst = side + (size_t)row * D + g * 4;
    atomicAdd(dst + 0, val * v.x);
    atomicAdd(dst + 1, val * v.y);
    atomicAdd(dst + 2, val * v.z);
    atomicAdd(dst + 3, val * v.w);
}

// ---------------------------------------------------------------------------
// Kernel 3: bi-interaction layer + l2norm epilogue.
//   sum_e = leaky_relu((ego+side) @ W1.T + b1)
//   bi_e  = leaky_relu((ego*side) @ W2.T + b2)
//   ego_next = sum_e + bi_e              -> ws (unnormalized, feeds next layer)
//   out[:, off:off+DOUT] = l2norm(ego_next)
// Block = 256 threads = NB nodes x DOUT lanes. Weights staged transposed
// (+1 pad -> conflict-free) in LDS; ego/side tiles staged in LDS (broadcast
// reads). l2norm via __shfl_xor within DOUT-lane groups (aligned to wave).
// ---------------------------------------------------------------------------
template <int DIN, int DOUT, int NB>
__global__ void layer_kernel(const float* __restrict__ ego,
                             const float* __restrict__ side,
                             const float* __restrict__ W1,
                             const float* __restrict__ b1,
                             const float* __restrict__ W2,
                             const float* __restrict__ b2,
                             float* __restrict__ ego_next,   // may be nullptr
                             float* __restrict__ out,
                             int out_off) {
    __shared__ float W1t[DIN][DOUT + 1];
    __shared__ float W2t[DIN][DOUT + 1];
    __shared__ float egoL[NB][DIN];
    __shared__ float sideL[NB][DIN];

    for (int i = threadIdx.x; i < DIN * DOUT; i += blockDim.x) {
        int j = i / DIN;
        int k = i - j * DIN;
        W1t[k][j] = W1[i];
        W2t[k][j] = W2[i];
    }
    int node0 = blockIdx.x * NB;
    for (int i = threadIdx.x; i < NB * DIN; i += blockDim.x) {
        int m = i / DIN;
        int k = i - m * DIN;
        int n = node0 + m;
        if (n < NN) {
            egoL[m][k] = ego[(size_t)n * DIN + k];
            sideL[m][k] = side[(size_t)n * DIN + k];
        }
    }
    __syncthreads();

    int m = threadIdx.x / DOUT;
    int j = threadIdx.x % DOUT;
    int n = node0 + m;
    if (n >= NN) return;

    float s = b1[j];
    float bb = b2[j];
#pragma unroll
    for (int k = 0; k < DIN; ++k) {
        float eg = egoL[m][k];
        float sd = sideL[m][k];
        s = fmaf(eg + sd, W1t[k][j], s);
        bb = fmaf(eg * sd, W2t[k][j], bb);
    }
    s = (s > 0.0f) ? s : 0.01f * s;      // leaky_relu, slope 0.01 (jax default)
    bb = (bb > 0.0f) ? bb : 0.01f * bb;
    float v = s + bb;
    if (ego_next) ego_next[(size_t)n * DOUT + j] = v;

    // l2 norm across the DOUT lanes of this node
    float sq = v * v;
#pragma unroll
    for (int off = DOUT / 2; off > 0; off >>= 1)
        sq += __shfl_xor(sq, off, DOUT);
    float norm = sqrtf(sq);
    norm = (norm > 1e-12f) ? norm : 1e-12f;
    out[(size_t)n * OUTD + out_off + j] = v / norm;
}

// ---------------------------------------------------------------------------
extern "C" void kernel_launch(void* const* d_in, const int* in_sizes, int n_in,
                              void* d_out, int out_size, void* d_ws, size_t ws_size,
                              hipStream_t stream) {
    const float* aux_info  = (const float*)d_in[0];   // [N,3]
    const float* entity    = (const float*)d_in[1];   // [N,64]
    const float* aux_W     = (const float*)d_in[2];   // [64,3]
    const float* aux_b     = (const float*)d_in[3];   // [64]
    const float* edge_vals = (const float*)d_in[4];   // [E]
    const int*   edge_rows = (const int*)d_in[5];     // [E]
    const int*   edge_cols = (const int*)d_in[6];     // [E]
    const float* W1_0 = (const float*)d_in[7];        // [32,64]
    const float* b1_0 = (const float*)d_in[8];
    const float* W2_0 = (const float*)d_in[9];
    const float* b2_0 = (const float*)d_in[10];
    const float* W1_1 = (const float*)d_in[11];       // [16,32]
    const float* b1_1 = (const float*)d_in[12];
    const float* W2_1 = (const float*)d_in[13];
    const float* b2_1 = (const float*)d_in[14];
    float* out = (float*)d_out;

    // workspace layout (fp32 elements): ego0[N*64] side0[N*64] ego1[N*32] side1[N*32]
    float* ego0  = (float*)d_ws;
    float* side0 = ego0 + (size_t)NN * 64;
    float* ego1  = side0 + (size_t)NN * 64;
    float* side1 = ego1 + (size_t)NN * 32;

    hipMemsetAsync(side0, 0, (size_t)NN * 64 * sizeof(float), stream);
    hipMemsetAsync(side1, 0, (size_t)NN * 32 * sizeof(float), stream);

    // 1) holographic fusion -> ego0, out[:,0:64]
    {
        int total = NN * 64;
        fuse_ego_kernel<<<(total + 255) / 256, 256, 0, stream>>>(
            aux_info, entity, aux_W, aux_b, ego0, out);
    }
    // 2) layer 0 segment-sum
    {
        int total = NE * 16;   // 16 threads/edge for D=64
        scatter_kernel<64><<<(total + 255) / 256, 256, 0, stream>>>(
            ego0, edge_vals, edge_rows, edge_cols, side0);
    }
    // 3) layer 0 transform -> ego1, out[:,64:96]
    layer_kernel<64, 32, 8><<<(NN + 7) / 8, 256, 0, stream>>>(
        ego0, side0, W1_0, b1_0, W2_0, b2_0, ego1, out, 64);
    // 4) layer 1 segment-sum
    {
        int total = NE * 8;    // 8 threads/edge for D=32
        scatter_kernel<32><<<(total + 255) / 256, 256, 0, stream>>>(
            ego1, edge_vals, edge_rows, edge_cols, side1);
    }
    // 5) layer 1 transform -> out[:,96:112]
    layer_kernel<32, 16, 16><<<(NN + 15) / 16, 256, 0, stream>>>(
        ego1, side1, W1_1, b1_1, W2_1, b2_1, nullptr, out, 96);
}

// Round 2
// 925.886 us; speedup vs baseline: 4.5301x; 4.5301x over previous
//
#include <hip/hip_runtime.h>
#include <math.h>

#define NN 100000
#define NE 3200000
#define OUTD 112
#define SCAN_T 1024

// ---------------------------------------------------------------------------
// Kernel 1: ego = entity_embed * (1 + tanh(aux_info @ aux_W.T + aux_b))
// ---------------------------------------------------------------------------
__global__ void fuse_ego_kernel(const float* __restrict__ aux_info,
                                const float* __restrict__ entity,
                                const float* __restrict__ aux_W,
                                const float* __restrict__ aux_b,
                                float* __restrict__ ego0,
                                float* __restrict__ out) {
    int idx = blockIdx.x * blockDim.x + threadIdx.x;
    if (idx >= NN * 64) return;
    int n = idx >> 6;
    int j = idx & 63;
    float a0 = aux_info[n * 3 + 0];
    float a1 = aux_info[n * 3 + 1];
    float a2 = aux_info[n * 3 + 2];
    float w0 = aux_W[j * 3 + 0];
    float w1 = aux_W[j * 3 + 1];
    float w2 = aux_W[j * 3 + 2];
    float t = tanhf(fmaf(a0, w0, fmaf(a1, w1, fmaf(a2, w2, aux_b[j]))));
    float e = entity[idx] * (1.0f + t);
    ego0[idx] = e;
    out[(size_t)n * OUTD + j] = e;
}

// ---------------------------------------------------------------------------
// CSR build: histogram -> exclusive scan -> stable-ish fill (order within a
// row is arbitrary; segment-sum is order-insensitive up to fp rounding).
// ---------------------------------------------------------------------------
__global__ void hist_kernel(const int* __restrict__ rows, int* __restrict__ cnt) {
    int e = blockIdx.x * blockDim.x + threadIdx.x;
    if (e >= NE) return;
    atomicAdd(&cnt[rows[e]], 1);
}

// single-block exclusive scan of cnt[0..NN) -> row_ptr[0..NN]; zeroes cnt for
// reuse as the fill cursor.
__global__ void scan_kernel(int* __restrict__ cnt, int* __restrict__ row_ptr) {
    __shared__ int sums[SCAN_T];
    int t = threadIdx.x;
    const int CHUNK = (NN + SCAN_T - 1) / SCAN_T;
    int beg = t * CHUNK;
    int end = beg + CHUNK; if (end > NN) end = NN;
    int s = 0;
    for (int i = beg; i < end; ++i) s += cnt[i];
    sums[t] = s;
    __syncthreads();
    for (int off = 1; off < SCAN_T; off <<= 1) {
        int v = 0;
        if (t >= off) v = sums[t - off];
        __syncthreads();
        if (t >= off) sums[t] += v;
        __syncthreads();
    }
    int run = (t == 0) ? 0 : sums[t - 1];
    for (int i = beg; i < end; ++i) {
        int c = cnt[i];
        row_ptr[i] = run;
        run += c;
        cnt[i] = 0;
    }
    if (t == SCAN_T - 1) row_ptr[NN] = run;
}

__global__ void fill_kernel(const int* __restrict__ rows,
                            const int* __restrict__ cols,
                            const float* __restrict__ vals,
                            const int* __restrict__ row_ptr,
                            int* __restrict__ cursor,
                            int2* __restrict__ edges) {
    int e = blockIdx.x * blockDim.x + threadIdx.x;
    if (e >= NE) return;
    int r = rows[e];
    int p = row_ptr[r] + atomicAdd(&cursor[r], 1);
    edges[p] = make_int2(cols[e], __float_as_int(vals[e]));
}

// ---------------------------------------------------------------------------
// Pull-based segment sum: LPN lanes per node, lane j owns feature j.
// side[n][j] = sum_{edges of n} val * ego[col][j]
// ---------------------------------------------------------------------------
template <int D>
__global__ void gather_kernel(const float* __restrict__ ego,
                              const int2* __restrict__ edges,
                              const int* __restrict__ row_ptr,
                              float* __restrict__ side) {
    constexpr int LPN = D;                      // lanes per node
    int g = threadIdx.x / LPN;
    int n = blockIdx.x * (256 / LPN) + g;
    int j = threadIdx.x % LPN;
    if (n >= NN) return;
    int beg = row_ptr[n];
    int end = row_ptr[n + 1];
    float acc = 0.0f;
    int i = beg;
    for (; i + 4 <= end; i += 4) {
        int2 e0 = edges[i + 0];
        int2 e1 = edges[i + 1];
        int2 e2 = edges[i + 2];
        int2 e3 = edges[i + 3];
        float g0 = ego[(size_t)e0.x * D + j];
        float g1 = ego[(size_t)e1.x * D + j];
        float g2 = ego[(size_t)e2.x * D + j];
        float g3 = ego[(size_t)e3.x * D + j];
        acc = fmaf(__int_as_float(e0.y), g0, acc);
        acc = fmaf(__int_as_float(e1.y), g1, acc);
        acc = fmaf(__int_as_float(e2.y), g2, acc);
        acc = fmaf(__int_as_float(e3.y), g3, acc);
    }
    for (; i < end; ++i) {
        int2 e = edges[i];
        acc = fmaf(__int_as_float(e.y), ego[(size_t)e.x * D + j], acc);
    }
    side[(size_t)n * D + j] = acc;
}

// ---------------------------------------------------------------------------
// Bi-interaction layer + l2norm epilogue (unchanged from R1).
// ---------------------------------------------------------------------------
template <int DIN, int DOUT, int NB>
__global__ void layer_kernel(const float* __restrict__ ego,
                             const float* __restrict__ side,
                             const float* __restrict__ W1,
                             const float* __restrict__ b1,
                             const float* __restrict__ W2,
                             const float* __restrict__ b2,
                             float* __restrict__ ego_next,   // may be nullptr
                             float* __restrict__ out,
                             int out_off) {
    __shared__ float W1t[DIN][DOUT + 1];
    __shared__ float W2t[DIN][DOUT + 1];
    __shared__ float egoL[NB][DIN];
    __shared__ float sideL[NB][DIN];

    for (int i = threadIdx.x; i < DIN * DOUT; i += blockDim.x) {
        int j = i / DIN;
        int k = i - j * DIN;
        W1t[k][j] = W1[i];
        W2t[k][j] = W2[i];
    }
    int node0 = blockIdx.x * NB;
    for (int i = threadIdx.x; i < NB * DIN; i += blockDim.x) {
        int m = i / DIN;
        int k = i - m * DIN;
        int n = node0 + m;
        if (n < NN) {
            egoL[m][k] = ego[(size_t)n * DIN + k];
            sideL[m][k] = side[(size_t)n * DIN + k];
        }
    }
    __syncthreads();

    int m = threadIdx.x / DOUT;
    int j = threadIdx.x % DOUT;
    int n = node0 + m;
    if (n >= NN) return;

    float s = b1[j];
    float bb = b2[j];
#pragma unroll
    for (int k = 0; k < DIN; ++k) {
        float eg = egoL[m][k];
        float sd = sideL[m][k];
        s = fmaf(eg + sd, W1t[k][j], s);
        bb = fmaf(eg * sd, W2t[k][j], bb);
    }
    s = (s > 0.0f) ? s : 0.01f * s;
    bb = (bb > 0.0f) ? bb : 0.01f * bb;
    float v = s + bb;
    if (ego_next) ego_next[(size_t)n * DOUT + j] = v;

    float sq = v * v;
#pragma unroll
    for (int off = DOUT / 2; off > 0; off >>= 1)
        sq += __shfl_xor(sq, off, DOUT);
    float norm = sqrtf(sq);
    norm = (norm > 1e-12f) ? norm : 1e-12f;
    out[(size_t)n * OUTD + out_off + j] = v / norm;
}

// ---------------------------------------------------------------------------
extern "C" void kernel_launch(void* const* d_in, const int* in_sizes, int n_in,
                              void* d_out, int out_size, void* d_ws, size_t ws_size,
                              hipStream_t stream) {
    const float* aux_info  = (const float*)d_in[0];   // [N,3]
    const float* entity    = (const float*)d_in[1];   // [N,64]
    const float* aux_W     = (const float*)d_in[2];   // [64,3]
    const float* aux_b     = (const float*)d_in[3];   // [64]
    const float* edge_vals = (const float*)d_in[4];   // [E]
    const int*   edge_rows = (const int*)d_in[5];     // [E]
    const int*   edge_cols = (const int*)d_in[6];     // [E]
    const float* W1_0 = (const float*)d_in[7];        // [32,64]
    const float* b1_0 = (const float*)d_in[8];
    const float* W2_0 = (const float*)d_in[9];
    const float* b2_0 = (const float*)d_in[10];
    const float* W1_1 = (const float*)d_in[11];       // [16,32]
    const float* b1_1 = (const float*)d_in[12];
    const float* W2_1 = (const float*)d_in[13];
    const float* b2_1 = (const float*)d_in[14];
    float* out = (float*)d_out;

    // workspace layout (4-byte elements):
    // ego0[N*64] side0[N*64] ego1[N*32] side1[N*32] edges[2*E] row_ptr[N+1] cursor[N]
    float* ego0  = (float*)d_ws;
    float* side0 = ego0 + (size_t)NN * 64;
    float* ego1  = side0 + (size_t)NN * 64;
    float* side1 = ego1 + (size_t)NN * 32;
    int2*  edges = (int2*)(side1 + (size_t)NN * 32);
    int* row_ptr = (int*)(edges + NE);
    int* cursor  = row_ptr + NN + 1;

    // --- CSR build (once; both layers share the graph) ---
    hipMemsetAsync(cursor, 0, (size_t)NN * sizeof(int), stream);
    hist_kernel<<<(NE + 255) / 256, 256, 0, stream>>>(edge_rows, cursor);
    scan_kernel<<<1, SCAN_T, 0, stream>>>(cursor, row_ptr);
    fill_kernel<<<(NE + 255) / 256, 256, 0, stream>>>(
        edge_rows, edge_cols, edge_vals, row_ptr, cursor, edges);

    // --- 1) holographic fusion -> ego0, out[:,0:64] ---
    {
        int total = NN * 64;
        fuse_ego_kernel<<<(total + 255) / 256, 256, 0, stream>>>(
            aux_info, entity, aux_W, aux_b, ego0, out);
    }
    // --- 2) layer 0 segment-sum (pull) ---
    gather_kernel<64><<<(NN + 3) / 4, 256, 0, stream>>>(ego0, edges, row_ptr, side0);
    // --- 3) layer 0 transform -> ego1, out[:,64:96] ---
    layer_kernel<64, 32, 8><<<(NN + 7) / 8, 256, 0, stream>>>(
        ego0, side0, W1_0, b1_0, W2_0, b2_0, ego1, out, 64);
    // --- 4) layer 1 segment-sum (pull) ---
    gather_kernel<32><<<(NN + 7) / 8, 256, 0, stream>>>(ego1, edges, row_ptr, side1);
    // --- 5) layer 1 transform -> out[:,96:112] ---
    layer_kernel<32, 16, 16><<<(NN + 15) / 16, 256, 0, stream>>>(
        ego1, side1, W1_1, b1_1, W2_1, b2_1, nullptr, out, 96);
}

// Round 3
// 693.069 us; speedup vs baseline: 6.0519x; 1.3359x over previous
//
#include <hip/hip_runtime.h>
#include <math.h>

#define NN 100000
#define NE 3200000
#define OUTD 112
#define SCAN_B 98   // ceil(NN / 1024)

// ---------------------------------------------------------------------------
// Kernel 1: ego = entity_embed * (1 + tanh(aux_info @ aux_W.T + aux_b))
// ---------------------------------------------------------------------------
__global__ void fuse_ego_kernel(const float* __restrict__ aux_info,
                                const float* __restrict__ entity,
                                const float* __restrict__ aux_W,
                                const float* __restrict__ aux_b,
                                float* __restrict__ ego0,
                                float* __restrict__ out) {
    int idx = blockIdx.x * blockDim.x + threadIdx.x;
    if (idx >= NN * 64) return;
    int n = idx >> 6;
    int j = idx & 63;
    float a0 = aux_info[n * 3 + 0];
    float a1 = aux_info[n * 3 + 1];
    float a2 = aux_info[n * 3 + 2];
    float w0 = aux_W[j * 3 + 0];
    float w1 = aux_W[j * 3 + 1];
    float w2 = aux_W[j * 3 + 2];
    float t = tanhf(fmaf(a0, w0, fmaf(a1, w1, fmaf(a2, w2, aux_b[j]))));
    float e = entity[idx] * (1.0f + t);
    ego0[idx] = e;
    out[(size_t)n * OUTD + j] = e;
}

// ---------------------------------------------------------------------------
// CSR build: histogram -> hierarchical exclusive scan -> fill.
// ---------------------------------------------------------------------------
__global__ void hist_kernel(const int* __restrict__ rows, int* __restrict__ cnt) {
    int e = blockIdx.x * blockDim.x + threadIdx.x;
    if (e >= NE) return;
    atomicAdd(&cnt[rows[e]], 1);
}

// scanA: per-block (1024 counts) reduction -> bsum[b]
__global__ void scanA_kernel(const int* __restrict__ cnt, int* __restrict__ bsum) {
    __shared__ int red[256];
    int b = blockIdx.x, t = threadIdx.x;
    int base = b * 1024 + t * 4;
    int s = 0;
#pragma unroll
    for (int k = 0; k < 4; ++k) {
        int i = base + k;
        if (i < NN) s += cnt[i];
    }
    red[t] = s;
    __syncthreads();
    for (int off = 128; off > 0; off >>= 1) {
        if (t < off) red[t] += red[t + off];
        __syncthreads();
    }
    if (t == 0) bsum[b] = red[0];
}

// scanB: one tiny block scans the SCAN_B block sums -> boff (exclusive);
// also writes row_ptr[NN] = total.
__global__ void scanB_kernel(const int* __restrict__ bsum,
                             int* __restrict__ boff,
                             int* __restrict__ row_ptr) {
    __shared__ int sh[128];
    int t = threadIdx.x;
    int v = (t < SCAN_B) ? bsum[t] : 0;
    sh[t] = v;
    __syncthreads();
    for (int off = 1; off < 128; off <<= 1) {
        int u = (t >= off) ? sh[t - off] : 0;
        __syncthreads();
        sh[t] += u;
        __syncthreads();
    }
    if (t < SCAN_B) boff[t] = sh[t] - v;   // exclusive
    if (t == 127) row_ptr[NN] = sh[127];
}

// scanC: per-block exclusive scan + block offset -> row_ptr; zero cnt (cursor).
__global__ void scanC_kernel(int* __restrict__ cnt,
                             const int* __restrict__ boff,
                             int* __restrict__ row_ptr) {
    __shared__ int sh[256];
    int b = blockIdx.x, t = threadIdx.x;
    int base = b * 1024 + t * 4;
    int c[4];
    int s = 0;
#pragma unroll
    for (int k = 0; k < 4; ++k) {
        int i = base + k;
        c[k] = (i < NN) ? cnt[i] : 0;
        s += c[k];
    }
    sh[t] = s;
    __syncthreads();
    for (int off = 1; off < 256; off <<= 1) {
        int u = (t >= off) ? sh[t - off] : 0;
        __syncthreads();
        sh[t] += u;
        __syncthreads();
    }
    int run = boff[b] + ((t == 0) ? 0 : sh[t - 1]);
#pragma unroll
    for (int k = 0; k < 4; ++k) {
        int i = base + k;
        if (i < NN) {
            row_ptr[i] = run;
            run += c[k];
            cnt[i] = 0;
        }
    }
}

__global__ void fill_kernel(const int* __restrict__ rows,
                            const int* __restrict__ cols,
                            const float* __restrict__ vals,
                            const int* __restrict__ row_ptr,
                            int* __restrict__ cursor,
                            int2* __restrict__ edges) {
    int e = blockIdx.x * blockDim.x + threadIdx.x;
    if (e >= NE) return;
    int r = rows[e];
    int p = row_ptr[r] + atomicAdd(&cursor[r], 1);
    edges[p] = make_int2(cols[e], __float_as_int(vals[e]));
}

// ---------------------------------------------------------------------------
// Pull-based segment sum: D lanes per node, lane j owns feature j.
// ---------------------------------------------------------------------------
template <int D>
__global__ void gather_kernel(const float* __restrict__ ego,
                              const int2* __restrict__ edges,
                              const int* __restrict__ row_ptr,
                              float* __restrict__ side) {
    int g = threadIdx.x / D;
    int n = blockIdx.x * (256 / D) + g;
    int j = threadIdx.x % D;
    if (n >= NN) return;
    int beg = row_ptr[n];
    int end = row_ptr[n + 1];
    float acc = 0.0f;
    int i = beg;
    for (; i + 8 <= end; i += 8) {
        int2 e[8];
        float gv[8];
#pragma unroll
        for (int k = 0; k < 8; ++k) e[k] = edges[i + k];
#pragma unroll
        for (int k = 0; k < 8; ++k) gv[k] = ego[(size_t)e[k].x * D + j];
#pragma unroll
        for (int k = 0; k < 8; ++k) acc = fmaf(__int_as_float(e[k].y), gv[k], acc);
    }
    for (; i < end; ++i) {
        int2 e = edges[i];
        acc = fmaf(__int_as_float(e.y), ego[(size_t)e.x * D + j], acc);
    }
    side[(size_t)n * D + j] = acc;
}

// ---------------------------------------------------------------------------
// Bi-interaction layer + l2norm epilogue.
// ---------------------------------------------------------------------------
template <int DIN, int DOUT, int NB>
__global__ void layer_kernel(const float* __restrict__ ego,
                             const float* __restrict__ side,
                             const float* __restrict__ W1,
                             const float* __restrict__ b1,
                             const float* __restrict__ W2,
                             const float* __restrict__ b2,
                             float* __restrict__ ego_next,   // may be nullptr
                             float* __restrict__ out,
                             int out_off) {
    __shared__ float W1t[DIN][DOUT + 1];
    __shared__ float W2t[DIN][DOUT + 1];
    __shared__ float egoL[NB][DIN];
    __shared__ float sideL[NB][DIN];

    for (int i = threadIdx.x; i < DIN * DOUT; i += blockDim.x) {
        int j = i / DIN;
        int k = i - j * DIN;
        W1t[k][j] = W1[i];
        W2t[k][j] = W2[i];
    }
    int node0 = blockIdx.x * NB;
    for (int i = threadIdx.x; i < NB * DIN; i += blockDim.x) {
        int m = i / DIN;
        int k = i - m * DIN;
        int n = node0 + m;
        if (n < NN) {
            egoL[m][k] = ego[(size_t)n * DIN + k];
            sideL[m][k] = side[(size_t)n * DIN + k];
        }
    }
    __syncthreads();

    int m = threadIdx.x / DOUT;
    int j = threadIdx.x % DOUT;
    int n = node0 + m;
    if (n >= NN) return;

    float s = b1[j];
    float bb = b2[j];
#pragma unroll
    for (int k = 0; k < DIN; ++k) {
        float eg = egoL[m][k];
        float sd = sideL[m][k];
        s = fmaf(eg + sd, W1t[k][j], s);
        bb = fmaf(eg * sd, W2t[k][j], bb);
    }
    s = (s > 0.0f) ? s : 0.01f * s;
    bb = (bb > 0.0f) ? bb : 0.01f * bb;
    float v = s + bb;
    if (ego_next) ego_next[(size_t)n * DOUT + j] = v;

    float sq = v * v;
#pragma unroll
    for (int off = DOUT / 2; off > 0; off >>= 1)
        sq += __shfl_xor(sq, off, DOUT);
    float norm = sqrtf(sq);
    norm = (norm > 1e-12f) ? norm : 1e-12f;
    out[(size_t)n * OUTD + out_off + j] = v / norm;
}

// ---------------------------------------------------------------------------
extern "C" void kernel_launch(void* const* d_in, const int* in_sizes, int n_in,
                              void* d_out, int out_size, void* d_ws, size_t ws_size,
                              hipStream_t stream) {
    const float* aux_info  = (const float*)d_in[0];
    const float* entity    = (const float*)d_in[1];
    const float* aux_W     = (const float*)d_in[2];
    const float* aux_b     = (const float*)d_in[3];
    const float* edge_vals = (const float*)d_in[4];
    const int*   edge_rows = (const int*)d_in[5];
    const int*   edge_cols = (const int*)d_in[6];
    const float* W1_0 = (const float*)d_in[7];
    const float* b1_0 = (const float*)d_in[8];
    const float* W2_0 = (const float*)d_in[9];
    const float* b2_0 = (const float*)d_in[10];
    const float* W1_1 = (const float*)d_in[11];
    const float* b1_1 = (const float*)d_in[12];
    const float* W2_1 = (const float*)d_in[13];
    const float* b2_1 = (const float*)d_in[14];
    float* out = (float*)d_out;

    // workspace layout (4-byte elements):
    // ego0[N*64] side0[N*64] ego1[N*32] side1[N*32] edges[2*E]
    // row_ptr[N+1] cursor[N] bsum[SCAN_B] boff[SCAN_B]
    float* ego0  = (float*)d_ws;
    float* side0 = ego0 + (size_t)NN * 64;
    float* ego1  = side0 + (size_t)NN * 64;
    float* side1 = ego1 + (size_t)NN * 32;
    int2*  edges = (int2*)(side1 + (size_t)NN * 32);
    int* row_ptr = (int*)(edges + NE);
    int* cursor  = row_ptr + NN + 1;
    int* bsum    = cursor + NN;
    int* boff    = bsum + SCAN_B;

    // --- CSR build (counting sort by row; graph shared by both layers) ---
    hipMemsetAsync(cursor, 0, (size_t)NN * sizeof(int), stream);
    hist_kernel<<<(NE + 255) / 256, 256, 0, stream>>>(edge_rows, cursor);
    scanA_kernel<<<SCAN_B, 256, 0, stream>>>(cursor, bsum);
    scanB_kernel<<<1, 128, 0, stream>>>(bsum, boff, row_ptr);
    scanC_kernel<<<SCAN_B, 256, 0, stream>>>(cursor, boff, row_ptr);
    fill_kernel<<<(NE + 255) / 256, 256, 0, stream>>>(
        edge_rows, edge_cols, edge_vals, row_ptr, cursor, edges);

    // --- 1) holographic fusion -> ego0, out[:,0:64] ---
    {
        int total = NN * 64;
        fuse_ego_kernel<<<(total + 255) / 256, 256, 0, stream>>>(
            aux_info, entity, aux_W, aux_b, ego0, out);
    }
    // --- 2) layer 0 segment-sum (pull) ---
    gather_kernel<64><<<(NN + 3) / 4, 256, 0, stream>>>(ego0, edges, row_ptr, side0);
    // --- 3) layer 0 transform -> ego1, out[:,64:96] ---
    layer_kernel<64, 32, 8><<<(NN + 7) / 8, 256, 0, stream>>>(
        ego0, side0, W1_0, b1_0, W2_0, b2_0, ego1, out, 64);
    // --- 4) layer 1 segment-sum (pull) ---
    gather_kernel<32><<<(NN + 7) / 8, 256, 0, stream>>>(ego1, edges, row_ptr, side1);
    // --- 5) layer 1 transform -> out[:,96:112] ---
    layer_kernel<32, 16, 16><<<(NN + 15) / 16, 256, 0, stream>>>(
        ego1, side1, W1_1, b1_1, W2_1, b2_1, nullptr, out, 96);
}